// Round 9
// baseline (72.159 us; speedup 1.0000x reference)
//
#include <hip/hip_runtime.h>
#include <hip/hip_bf16.h>

#define B_ 8
#define N_ 1024
#define FIN_ 256
#define H_ 8
#define F_ 64
#define HF_ 512
#define BN_ 8192
#define LOG2E 1.4426950408889634f

using bf16x8 = __attribute__((ext_vector_type(8))) short;
using f32x4  = __attribute__((ext_vector_type(4))) float;
using i32x4  = __attribute__((ext_vector_type(4))) int;

__device__ __forceinline__ short f2bf(float x) {
  __hip_bfloat16 b = __float2bfloat16(x);
  return *reinterpret_cast<short*>(&b);
}
__device__ __forceinline__ float bf2f(short s) {
  union { unsigned u; float f; } v;
  v.u = ((unsigned)(unsigned short)s) << 16;
  return v.f;
}
__device__ __forceinline__ bf16x8 cvtCE(f32x4 pa, f32x4 pb, i32x4 ma, i32x4 mb, float es) {
  bf16x8 o;
#pragma unroll
  for (int e = 0; e < 4; e++) {
    o[e]     = f2bf(ma[e] != 0 ? es * pa[e] : -1e30f);
    o[e + 4] = f2bf(mb[e] != 0 ? es * pb[e] : -1e30f);
  }
  return o;
}

// K0: xb = bf16(x) (blocks 0..1023); Wt[f][c] = bf16(W[c][f]) (blocks 1024..1535)
__global__ __launch_bounds__(256) void k_cvt(
    const float* __restrict__ x, const float* __restrict__ W,
    short* __restrict__ xb, short* __restrict__ Wt) {
  const int bid = blockIdx.x;
  if (bid < 1024) {
    const int idx = (bid * 256 + threadIdx.x) * 8;
    f32x4 a = *(const f32x4*)(x + idx);
    f32x4 b = *(const f32x4*)(x + idx + 4);
    bf16x8 o;
    o[0]=f2bf(a[0]); o[1]=f2bf(a[1]); o[2]=f2bf(a[2]); o[3]=f2bf(a[3]);
    o[4]=f2bf(b[0]); o[5]=f2bf(b[1]); o[6]=f2bf(b[2]); o[7]=f2bf(b[3]);
    *(bf16x8*)(xb + idx) = o;
  } else {
    const int idx = (bid - 1024) * 256 + threadIdx.x;
    const int f = idx >> 8, c = idx & 255;
    Wt[f * FIN_ + c] = f2bf(W[c * HF_ + f]);
  }
}

// K1: h = x@W per-head 64f x 64n tile, fused el/er epilogue; writes hA in
// MFMA-A-fragment order via LDS transpose (j local to b):
// hAg[((b8h*32+js)*4+ff)*512 + l*8 + e] = h[h*64+ff*16+(l&15)][js*32+(l>>4)*8+e]
__global__ __launch_bounds__(256) void k_h(
    const short* __restrict__ Wt, const short* __restrict__ xb,
    const float* __restrict__ aL, const float* __restrict__ aR,
    short* __restrict__ hAg, float* __restrict__ el_t, float* __restrict__ er_t) {
  const int nt = blockIdx.x;
  const int h  = blockIdx.y;
  const int w  = threadIdx.x >> 6;
  const int l  = threadIdx.x & 63;
  const int lr = l & 15, lk = l >> 4;
  const int n0 = nt * 64;
  const int fbase = h * 64 + w * 16;

  f32x4 acc[4] = {};
  const short* arow = Wt + (fbase + lr) * FIN_ + lk * 8;

#pragma unroll
  for (int k0 = 0; k0 < FIN_; k0 += 32) {
    bf16x8 a = *(const bf16x8*)(arow + k0);
#pragma unroll
    for (int nf = 0; nf < 4; nf++) {
      bf16x8 bb = *(const bf16x8*)(xb + (size_t)(n0 + nf * 16 + lr) * FIN_ + k0 + lk * 8);
      acc[nf] = __builtin_amdgcn_mfma_f32_16x16x32_bf16(a, bb, acc[nf], 0, 0, 0);
    }
  }

  __shared__ short sT[64][72];
  __shared__ float sEl[4][64], sEr[4][64];
  float al[4], ar[4];
#pragma unroll
  for (int r = 0; r < 4; r++) {
    const int fl = w * 16 + lk * 4 + r;
    al[r] = aL[h * F_ + fl];
    ar[r] = aR[h * F_ + fl];
  }
#pragma unroll
  for (int nf = 0; nf < 4; nf++) {
    const int nl = nf * 16 + lr;
#pragma unroll
    for (int r = 0; r < 4; r++)
      sT[w * 16 + lk * 4 + r][nl] = f2bf(acc[nf][r]);
    float pl = acc[nf][0]*al[0] + acc[nf][1]*al[1] + acc[nf][2]*al[2] + acc[nf][3]*al[3];
    float pr = acc[nf][0]*ar[0] + acc[nf][1]*ar[1] + acc[nf][2]*ar[2] + acc[nf][3]*ar[3];
    pl += __shfl_xor(pl, 16); pl += __shfl_xor(pl, 32);
    pr += __shfl_xor(pr, 16); pr += __shfl_xor(pr, 32);
    if (lk == 0) { sEl[w][nl] = pl; sEr[w][nl] = pr; }
  }
  __syncthreads();
  if (threadIdx.x < 64) {
    const int n = threadIdx.x;
    el_t[h * BN_ + n0 + n] = (sEl[0][n] + sEl[1][n] + sEl[2][n] + sEl[3][n]) * LOG2E;
    er_t[h * BN_ + n0 + n] = (sEr[0][n] + sEr[1][n] + sEr[2][n] + sEr[3][n]) * LOG2E;
  }
  const int b8h = (nt >> 4) * 8 + h;
  const int jb  = (nt & 15) * 2;
#pragma unroll
  for (int gi = 0; gi < 2; gi++) {
    const int g   = threadIdx.x * 2 + gi;
    const int jsl = g >> 8, ff = (g >> 6) & 3, gl = g & 63;
    const int glr = gl & 15, glk = gl >> 4;
    bf16x8 v = *(const bf16x8*)(&sT[ff * 16 + glr][jsl * 32 + glk * 8]);
    *(bf16x8*)(hAg + (((size_t)b8h * 32 + jb + jsl) * 4 + ff) * 512 + gl * 8) = v;
  }
}

// K2: fused attention v9. Block = (b, 32-row i-tile) x 8 waves = ALL 8 heads
// -> prior/mask staged ONCE per row (64 MB total, no duplication), in 256-col
// chunks double-buffered in LDS: loads issued at chunk start (nontemporal, so
// the read-once stream doesn't evict hA from L2), LDS-write after the chunk's
// 8 compute steps, one barrier per chunk -> staging fully overlaps compute.
// Wave = head, 2 i-frags/wave, depth-2 register prefetch of h/er, no-max
// softmax, ones-MFMA denominator.
#define PREF_G(sn, Hd, E0d, E1d)                                      \
  {                                                                   \
    const short* hs_ = hW + (size_t)(sn) * 2048;                      \
    Hd[0] = *(const bf16x8*)(hs_);                                    \
    Hd[1] = *(const bf16x8*)(hs_ + 512);                              \
    Hd[2] = *(const bf16x8*)(hs_ + 1024);                             \
    Hd[3] = *(const bf16x8*)(hs_ + 1536);                             \
    E0d   = *(const f32x4*)(erp + (sn) * 32);                         \
    E1d   = *(const f32x4*)(erp + (sn) * 32 + 4);                     \
  }

#define PREF_C(cbp, js, C0d, C1d)                                     \
  {                                                                   \
    const int gi_ = ((((js) * 4 + lk) ^ xsw) * 8);                    \
    C0d = *(const bf16x8*)((cbp) + lr * 256 + gi_);                   \
    C1d = *(const bf16x8*)((cbp) + 4096 + lr * 256 + gi_);            \
  }

#define STAGE_LOAD(ch)                                                \
  {                                                                   \
    const float* pp_ = rowp + (ch) * 256;                             \
    const int*   mm_ = rowm + (ch) * 256;                             \
    sp0 = __builtin_nontemporal_load((const f32x4*)(pp_));            \
    sp1 = __builtin_nontemporal_load((const f32x4*)(pp_ + 4));        \
    sp2 = __builtin_nontemporal_load((const f32x4*)(pp_ + 8));        \
    sp3 = __builtin_nontemporal_load((const f32x4*)(pp_ + 12));       \
    sm0 = __builtin_nontemporal_load((const i32x4*)(mm_));            \
    sm1 = __builtin_nontemporal_load((const i32x4*)(mm_ + 4));        \
    sm2 = __builtin_nontemporal_load((const i32x4*)(mm_ + 8));        \
    sm3 = __builtin_nontemporal_load((const i32x4*)(mm_ + 12));       \
  }

#define STAGE_WRITE(cbw)                                              \
  {                                                                   \
    *(bf16x8*)((cbw) + rbase + g0s) = cvtCE(sp0, sp1, sm0, sm1, es);  \
    *(bf16x8*)((cbw) + rbase + g1s) = cvtCE(sp2, sp3, sm2, sm3, es);  \
  }

#define COMP2(Hu, C0u, C1u, E0u, E1u)                                          \
  {                                                                            \
    bf16x8 pfA, pfB;                                                           \
    _Pragma("unroll")                                                          \
    for (int q = 0; q < 4; q++) {                                              \
      const float e0 = E0u[q], e1 = E1u[q];                                    \
      float sA  = el0 + e0, sA2 = el0 + e1;                                    \
      float sB  = el1 + e0, sB2 = el1 + e1;                                    \
      float vA  = fmaf(0.6f, sA,  bf2f(C0u[q]));                               \
      vA  = fmaf(0.4f, fabsf(sA),  vA);                                        \
      float vA2 = fmaf(0.6f, sA2, bf2f(C0u[q + 4]));                           \
      vA2 = fmaf(0.4f, fabsf(sA2), vA2);                                       \
      float vB  = fmaf(0.6f, sB,  bf2f(C1u[q]));                               \
      vB  = fmaf(0.4f, fabsf(sB),  vB);                                        \
      float vB2 = fmaf(0.6f, sB2, bf2f(C1u[q + 4]));                           \
      vB2 = fmaf(0.4f, fabsf(sB2), vB2);                                       \
      float x1_, x2_, x3_, x4_;                                                \
      asm("v_exp_f32 %0, %1" : "=v"(x1_) : "v"(vA));                           \
      asm("v_exp_f32 %0, %1" : "=v"(x2_) : "v"(vA2));                          \
      asm("v_exp_f32 %0, %1" : "=v"(x3_) : "v"(vB));                           \
      asm("v_exp_f32 %0, %1" : "=v"(x4_) : "v"(vB2));                          \
      pfA[q] = f2bf(x1_); pfA[q + 4] = f2bf(x2_);                              \
      pfB[q] = f2bf(x3_); pfB[q + 4] = f2bf(x4_);                              \
    }                                                                          \
    __builtin_amdgcn_s_setprio(1);                                             \
    accSA   = __builtin_amdgcn_mfma_f32_16x16x32_bf16(ones, pfA, accSA, 0,0,0);\
    accSB   = __builtin_amdgcn_mfma_f32_16x16x32_bf16(ones, pfB, accSB, 0,0,0);\
    accA[0] = __builtin_amdgcn_mfma_f32_16x16x32_bf16(Hu[0], pfA, accA[0],0,0,0);\
    accB[0] = __builtin_amdgcn_mfma_f32_16x16x32_bf16(Hu[0], pfB, accB[0],0,0,0);\
    accA[1] = __builtin_amdgcn_mfma_f32_16x16x32_bf16(Hu[1], pfA, accA[1],0,0,0);\
    accB[1] = __builtin_amdgcn_mfma_f32_16x16x32_bf16(Hu[1], pfB, accB[1],0,0,0);\
    accA[2] = __builtin_amdgcn_mfma_f32_16x16x32_bf16(Hu[2], pfA, accA[2],0,0,0);\
    accB[2] = __builtin_amdgcn_mfma_f32_16x16x32_bf16(Hu[2], pfB, accB[2],0,0,0);\
    accA[3] = __builtin_amdgcn_mfma_f32_16x16x32_bf16(Hu[3], pfA, accA[3],0,0,0);\
    accB[3] = __builtin_amdgcn_mfma_f32_16x16x32_bf16(Hu[3], pfB, accB[3],0,0,0);\
    __builtin_amdgcn_s_setprio(0);                                             \
  }

__global__ __launch_bounds__(512, 2) void k_attn(
    const short* __restrict__ hAg, const float* __restrict__ el_t,
    const float* __restrict__ er_t, const float* __restrict__ prior,
    const int* __restrict__ mask, const float* __restrict__ esp,
    float* __restrict__ out) {
  const int bid = blockIdx.x;
  const int b  = bid & 7;           // XCD = bid % 8
  const int it = bid >> 3;          // 0..31
  const int t  = threadIdx.x;       // 512 threads = 8 waves
  const int h  = t >> 6;            // wave = head
  const int l  = t & 63;
  const int lr = l & 15, lk = l >> 4;
  const int i0 = it * 32;
  const size_t bn = (size_t)b * N_;
  const float es = esp[0] * LOG2E;

  __shared__ short cbuf[2][8192];   // 2 x (32 rows x 256 cols) bf16, 32 KB

  // staging geometry: thread -> (row r, 16 cols at sub*16), unique coverage
  const int r    = t >> 4;          // 0..31
  const int sub  = t & 15;
  const int rbase = r * 256;
  const int g0s  = ((sub * 2) ^ (r & 7)) * 8;
  const int g1s  = ((sub * 2 + 1) ^ (r & 7)) * 8;
  const float* rowp = prior + (bn + i0 + r) * (size_t)N_ + sub * 16;
  const int*   rowm = mask  + (bn + i0 + r) * (size_t)N_ + sub * 16;
  f32x4 sp0, sp1, sp2, sp3;
  i32x4 sm0, sm1, sm2, sm3;

  const float el0 = el_t[h * BN_ + bn + i0 + lr];
  const float el1 = el_t[h * BN_ + bn + i0 + 16 + lr];
  const float* erp = er_t + h * BN_ + bn + lk * 8;
  const short* hW  = hAg + (size_t)(b * 8 + h) * 65536 + l * 8;
  const int xsw = lr & 7;

  bf16x8 HA[4], HB[4], cA0, cA1, cB0, cB1;
  f32x4 eA0, eA1, eB0, eB1;

  f32x4 accA[4] = {}, accB[4] = {};
  f32x4 accSA = {}, accSB = {};
  bf16x8 ones;
#pragma unroll
  for (int e = 0; e < 8; e++) ones[e] = (short)0x3F80;

  // ---- prologue: stage chunk 0, prefetch h/er for steps 0,1 ----
  STAGE_LOAD(0);
  __builtin_amdgcn_sched_barrier(0);
  STAGE_WRITE(&cbuf[0][0]);
  PREF_G(0, HA, eA0, eA1);
  PREF_G(1, HB, eB0, eB1);
  __syncthreads();
  PREF_C(&cbuf[0][0], 0, cA0, cA1);
  PREF_C(&cbuf[0][0], 1, cB0, cB1);

  for (int ch = 0; ch < 4; ++ch) {
    const int s0 = ch * 8;
    const short* cbc = &cbuf[ch & 1][0];
    short*       cbn = &cbuf[(ch + 1) & 1][0];
    if (ch < 3) {                          // issue next chunk's stream early (T14)
      STAGE_LOAD(ch + 1);
      __builtin_amdgcn_sched_barrier(0);
    }
    COMP2(HA, cA0, cA1, eA0, eA1);  PREF_G(s0 + 2, HA, eA0, eA1);  PREF_C(cbc, 2, cA0, cA1);
    COMP2(HB, cB0, cB1, eB0, eB1);  PREF_G(s0 + 3, HB, eB0, eB1);  PREF_C(cbc, 3, cB0, cB1);
    COMP2(HA, cA0, cA1, eA0, eA1);  PREF_G(s0 + 4, HA, eA0, eA1);  PREF_C(cbc, 4, cA0, cA1);
    COMP2(HB, cB0, cB1, eB0, eB1);  PREF_G(s0 + 5, HB, eB0, eB1);  PREF_C(cbc, 5, cB0, cB1);
    COMP2(HA, cA0, cA1, eA0, eA1);  PREF_G(s0 + 6, HA, eA0, eA1);  PREF_C(cbc, 6, cA0, cA1);
    COMP2(HB, cB0, cB1, eB0, eB1);  PREF_G(s0 + 7, HB, eB0, eB1);  PREF_C(cbc, 7, cB0, cB1);
    COMP2(HA, cA0, cA1, eA0, eA1);
    { const int sn_ = (s0 + 8 > 31) ? 31 : s0 + 8; PREF_G(sn_, HA, eA0, eA1); }
    COMP2(HB, cB0, cB1, eB0, eB1);
    { const int sn_ = (s0 + 9 > 31) ? 31 : s0 + 9; PREF_G(sn_, HB, eB0, eB1); }
    if (ch < 3) {
      STAGE_WRITE(cbn);                    // write-late: loads had 8 steps to land
      __syncthreads();                     // publish chunk ch+1
      PREF_C(cbn, 0, cA0, cA1);
      PREF_C(cbn, 1, cB0, cB1);
    }
  }

  const float invA = 1.0f / accSA[0];
  const float invB = 1.0f / accSB[0];
  const size_t rowA = bn + i0 + lr;
  const size_t rowB = rowA + 16;
#pragma unroll
  for (int ff = 0; ff < 4; ff++) {
    f32x4 va = accA[ff], vb = accB[ff];
    va[0]*=invA; va[1]*=invA; va[2]*=invA; va[3]*=invA;
    vb[0]*=invB; vb[1]*=invB; vb[2]*=invB; vb[3]*=invB;
    __builtin_nontemporal_store(va, (f32x4*)(out + rowA * HF_ + h * 64 + ff * 16 + lk * 4));
    __builtin_nontemporal_store(vb, (f32x4*)(out + rowB * HF_ + h * 64 + ff * 16 + lk * 4));
  }
}

extern "C" void kernel_launch(void* const* d_in, const int* in_sizes, int n_in,
                              void* d_out, int out_size, void* d_ws, size_t ws_size,
                              hipStream_t stream) {
  const float* x     = (const float*)d_in[0];
  const int*   adj   = (const int*)  d_in[1];
  const float* prior = (const float*)d_in[2];
  const float* W     = (const float*)d_in[3];
  const float* aL    = (const float*)d_in[4];
  const float* aR    = (const float*)d_in[5];
  const float* es    = (const float*)d_in[6];
  float* out = (float*)d_out;

  char* ws = (char*)d_ws;
  short* hAg  = (short*)ws;                                 //  8 MB
  short* xb   = (short*)(ws + 8u  * 1024 * 1024);           //  4 MB
  short* Wt   = (short*)(ws + 12u * 1024 * 1024);           // 256 KB
  float* el_t = (float*)(ws + 12u * 1024 * 1024 + 262144);  // 256 KB
  float* er_t = (float*)(ws + 12u * 1024 * 1024 + 524288);  // 256 KB

  hipLaunchKernelGGL(k_cvt, dim3(1536), dim3(256), 0, stream, x, W, xb, Wt);
  hipLaunchKernelGGL(k_h,   dim3(128, 8), dim3(256), 0, stream,
                     Wt, xb, aL, aR, hAg, el_t, er_t);
  hipLaunchKernelGGL(k_attn, dim3(256), dim3(512), 0, stream,
                     hAg, el_t, er_t, prior, adj, es, out);
}

// Round 10
// 69.872 us; speedup vs baseline: 1.0327x; 1.0327x over previous
//
#include <hip/hip_runtime.h>
#include <hip/hip_bf16.h>

#define B_ 8
#define N_ 1024
#define FIN_ 256
#define H_ 8
#define F_ 64
#define HF_ 512
#define BN_ 8192
#define LOG2E 1.4426950408889634f

using bf16x8 = __attribute__((ext_vector_type(8))) short;
using f32x4  = __attribute__((ext_vector_type(4))) float;
using i32x4  = __attribute__((ext_vector_type(4))) int;

__device__ __forceinline__ short f2bf(float x) {
  __hip_bfloat16 b = __float2bfloat16(x);
  return *reinterpret_cast<short*>(&b);
}
__device__ __forceinline__ float bf2f(short s) {
  union { unsigned u; float f; } v;
  v.u = ((unsigned)(unsigned short)s) << 16;
  return v.f;
}
__device__ __forceinline__ bf16x8 cvtCE(f32x4 pa, f32x4 pb, i32x4 ma, i32x4 mb, float es) {
  bf16x8 o;
#pragma unroll
  for (int e = 0; e < 4; e++) {
    o[e]     = f2bf(ma[e] != 0 ? es * pa[e] : -1e30f);
    o[e + 4] = f2bf(mb[e] != 0 ? es * pb[e] : -1e30f);
  }
  return o;
}

// K0: xb = bf16(x) (blocks 0..1023); Wt[f][c] = bf16(W[c][f]) (blocks 1024..1535)
__global__ __launch_bounds__(256) void k_cvt(
    const float* __restrict__ x, const float* __restrict__ W,
    short* __restrict__ xb, short* __restrict__ Wt) {
  const int bid = blockIdx.x;
  if (bid < 1024) {
    const int idx = (bid * 256 + threadIdx.x) * 8;
    f32x4 a = *(const f32x4*)(x + idx);
    f32x4 b = *(const f32x4*)(x + idx + 4);
    bf16x8 o;
    o[0]=f2bf(a[0]); o[1]=f2bf(a[1]); o[2]=f2bf(a[2]); o[3]=f2bf(a[3]);
    o[4]=f2bf(b[0]); o[5]=f2bf(b[1]); o[6]=f2bf(b[2]); o[7]=f2bf(b[3]);
    *(bf16x8*)(xb + idx) = o;
  } else {
    const int idx = (bid - 1024) * 256 + threadIdx.x;
    const int f = idx >> 8, c = idx & 255;
    Wt[f * FIN_ + c] = f2bf(W[c * HF_ + f]);
  }
}

// K1: h = x@W per-head 64f x 64n tile, fused el/er epilogue; writes hA in
// MFMA-A-fragment order via LDS transpose (j local to b):
// hAg[((b8h*32+js)*4+ff)*512 + l*8 + e] = h[h*64+ff*16+(l&15)][js*32+(l>>4)*8+e]
__global__ __launch_bounds__(256) void k_h(
    const short* __restrict__ Wt, const short* __restrict__ xb,
    const float* __restrict__ aL, const float* __restrict__ aR,
    short* __restrict__ hAg, float* __restrict__ el_t, float* __restrict__ er_t) {
  const int nt = blockIdx.x;
  const int h  = blockIdx.y;
  const int w  = threadIdx.x >> 6;
  const int l  = threadIdx.x & 63;
  const int lr = l & 15, lk = l >> 4;
  const int n0 = nt * 64;
  const int fbase = h * 64 + w * 16;

  f32x4 acc[4] = {};
  const short* arow = Wt + (fbase + lr) * FIN_ + lk * 8;

#pragma unroll
  for (int k0 = 0; k0 < FIN_; k0 += 32) {
    bf16x8 a = *(const bf16x8*)(arow + k0);
#pragma unroll
    for (int nf = 0; nf < 4; nf++) {
      bf16x8 bb = *(const bf16x8*)(xb + (size_t)(n0 + nf * 16 + lr) * FIN_ + k0 + lk * 8);
      acc[nf] = __builtin_amdgcn_mfma_f32_16x16x32_bf16(a, bb, acc[nf], 0, 0, 0);
    }
  }

  __shared__ short sT[64][72];
  __shared__ float sEl[4][64], sEr[4][64];
  float al[4], ar[4];
#pragma unroll
  for (int r = 0; r < 4; r++) {
    const int fl = w * 16 + lk * 4 + r;
    al[r] = aL[h * F_ + fl];
    ar[r] = aR[h * F_ + fl];
  }
#pragma unroll
  for (int nf = 0; nf < 4; nf++) {
    const int nl = nf * 16 + lr;
#pragma unroll
    for (int r = 0; r < 4; r++)
      sT[w * 16 + lk * 4 + r][nl] = f2bf(acc[nf][r]);
    float pl = acc[nf][0]*al[0] + acc[nf][1]*al[1] + acc[nf][2]*al[2] + acc[nf][3]*al[3];
    float pr = acc[nf][0]*ar[0] + acc[nf][1]*ar[1] + acc[nf][2]*ar[2] + acc[nf][3]*ar[3];
    pl += __shfl_xor(pl, 16); pl += __shfl_xor(pl, 32);
    pr += __shfl_xor(pr, 16); pr += __shfl_xor(pr, 32);
    if (lk == 0) { sEl[w][nl] = pl; sEr[w][nl] = pr; }
  }
  __syncthreads();
  if (threadIdx.x < 64) {
    const int n = threadIdx.x;
    el_t[h * BN_ + n0 + n] = (sEl[0][n] + sEl[1][n] + sEl[2][n] + sEl[3][n]) * LOG2E;
    er_t[h * BN_ + n0 + n] = (sEr[0][n] + sEr[1][n] + sEr[2][n] + sEr[3][n]) * LOG2E;
  }
  const int b8h = (nt >> 4) * 8 + h;
  const int jb  = (nt & 15) * 2;
#pragma unroll
  for (int gi = 0; gi < 2; gi++) {
    const int g   = threadIdx.x * 2 + gi;
    const int jsl = g >> 8, ff = (g >> 6) & 3, gl = g & 63;
    const int glr = gl & 15, glk = gl >> 4;
    bf16x8 v = *(const bf16x8*)(&sT[ff * 16 + glr][jsl * 32 + glk * 8]);
    *(bf16x8*)(hAg + (((size_t)b8h * 32 + jb + jsl) * 4 + ff) * 512 + gl * 8) = v;
  }
}

// K2 v10: 4 i-frags per wave (64-row tiles) -> every 4KB h/er prefetch feeds
// 4 P-fragments; h L3 traffic 256->128 MB (testing L3-BW-bound theory).
// Block = 256 thr = 4 waves = 4 heads (hp = head half). Grid = 8b*2hp*16it = 256.
// c staged in 64KB LDS double-buffer (64 rows x 256-col chunks); stage loads
// issued one step before their ds_write; one barrier per chunk.
#define PREF_G(sn, Hd, E0d, E1d)                                      \
  {                                                                   \
    const short* hs_ = hW + (size_t)(sn) * 2048;                      \
    Hd[0] = *(const bf16x8*)(hs_);                                    \
    Hd[1] = *(const bf16x8*)(hs_ + 512);                              \
    Hd[2] = *(const bf16x8*)(hs_ + 1024);                             \
    Hd[3] = *(const bf16x8*)(hs_ + 1536);                             \
    E0d   = *(const f32x4*)(erp + (sn) * 32);                         \
    E1d   = *(const f32x4*)(erp + (sn) * 32 + 4);                     \
  }

#define PREF_C4(cbp, js, Cd)                                          \
  {                                                                   \
    const int gi_ = (((js) * 4 + lk) ^ xsw) * 8;                      \
    Cd[0] = *(const bf16x8*)((cbp) + lr * 256 + gi_);                 \
    Cd[1] = *(const bf16x8*)((cbp) + (16 + lr) * 256 + gi_);          \
    Cd[2] = *(const bf16x8*)((cbp) + (32 + lr) * 256 + gi_);          \
    Cd[3] = *(const bf16x8*)((cbp) + (48 + lr) * 256 + gi_);          \
  }

#define SLOAD(ch1, js)                                                \
  {                                                                   \
    const float* pp_ = rowp + (ch1) * 256 + (js) * 8;                 \
    const int*   mm_ = rowm + (ch1) * 256 + (js) * 8;                 \
    sp0 = *(const f32x4*)(pp_); sp1 = *(const f32x4*)(pp_ + 4);       \
    sm0 = *(const i32x4*)(mm_); sm1 = *(const i32x4*)(mm_ + 4);       \
  }

#define SWRITE(bufp, js)                                              \
  {                                                                   \
    *(bf16x8*)((bufp) + rbase + (((sgrp + (js)) ^ rsw) * 8)) =        \
        cvtCE(sp0, sp1, sm0, sm1, es);                                \
  }

#define LGT(elv, ee, cc, dst)                                         \
  {                                                                   \
    float t_ = (elv) + (ee);                                          \
    float v_ = fmaf(0.4f, fabsf(t_), fmaf(0.6f, t_, bf2f(cc)));       \
    float x_;                                                         \
    asm("v_exp_f32 %0, %1" : "=v"(x_) : "v"(v_));                     \
    dst = f2bf(x_);                                                   \
  }

#define COMP4(Hu, Cu, E0u, E1u)                                                 \
  {                                                                             \
    bf16x8 pf0, pf1, pf2, pf3;                                                  \
    _Pragma("unroll")                                                           \
    for (int q = 0; q < 4; q++) {                                               \
      const float e0 = E0u[q], e1 = E1u[q];                                     \
      LGT(el0, e0, Cu[0][q], pf0[q]); LGT(el0, e1, Cu[0][q + 4], pf0[q + 4]);   \
      LGT(el1, e0, Cu[1][q], pf1[q]); LGT(el1, e1, Cu[1][q + 4], pf1[q + 4]);   \
      LGT(el2, e0, Cu[2][q], pf2[q]); LGT(el2, e1, Cu[2][q + 4], pf2[q + 4]);   \
      LGT(el3, e0, Cu[3][q], pf3[q]); LGT(el3, e1, Cu[3][q + 4], pf3[q + 4]);   \
    }                                                                           \
    __builtin_amdgcn_s_setprio(1);                                              \
    accS[0] = __builtin_amdgcn_mfma_f32_16x16x32_bf16(ones, pf0, accS[0],0,0,0);\
    accS[1] = __builtin_amdgcn_mfma_f32_16x16x32_bf16(ones, pf1, accS[1],0,0,0);\
    accS[2] = __builtin_amdgcn_mfma_f32_16x16x32_bf16(ones, pf2, accS[2],0,0,0);\
    accS[3] = __builtin_amdgcn_mfma_f32_16x16x32_bf16(ones, pf3, accS[3],0,0,0);\
    acc[0][0] = __builtin_amdgcn_mfma_f32_16x16x32_bf16(Hu[0], pf0, acc[0][0],0,0,0);\
    acc[0][1] = __builtin_amdgcn_mfma_f32_16x16x32_bf16(Hu[0], pf1, acc[0][1],0,0,0);\
    acc[0][2] = __builtin_amdgcn_mfma_f32_16x16x32_bf16(Hu[0], pf2, acc[0][2],0,0,0);\
    acc[0][3] = __builtin_amdgcn_mfma_f32_16x16x32_bf16(Hu[0], pf3, acc[0][3],0,0,0);\
    acc[1][0] = __builtin_amdgcn_mfma_f32_16x16x32_bf16(Hu[1], pf0, acc[1][0],0,0,0);\
    acc[1][1] = __builtin_amdgcn_mfma_f32_16x16x32_bf16(Hu[1], pf1, acc[1][1],0,0,0);\
    acc[1][2] = __builtin_amdgcn_mfma_f32_16x16x32_bf16(Hu[1], pf2, acc[1][2],0,0,0);\
    acc[1][3] = __builtin_amdgcn_mfma_f32_16x16x32_bf16(Hu[1], pf3, acc[1][3],0,0,0);\
    acc[2][0] = __builtin_amdgcn_mfma_f32_16x16x32_bf16(Hu[2], pf0, acc[2][0],0,0,0);\
    acc[2][1] = __builtin_amdgcn_mfma_f32_16x16x32_bf16(Hu[2], pf1, acc[2][1],0,0,0);\
    acc[2][2] = __builtin_amdgcn_mfma_f32_16x16x32_bf16(Hu[2], pf2, acc[2][2],0,0,0);\
    acc[2][3] = __builtin_amdgcn_mfma_f32_16x16x32_bf16(Hu[2], pf3, acc[2][3],0,0,0);\
    acc[3][0] = __builtin_amdgcn_mfma_f32_16x16x32_bf16(Hu[3], pf0, acc[3][0],0,0,0);\
    acc[3][1] = __builtin_amdgcn_mfma_f32_16x16x32_bf16(Hu[3], pf1, acc[3][1],0,0,0);\
    acc[3][2] = __builtin_amdgcn_mfma_f32_16x16x32_bf16(Hu[3], pf2, acc[3][2],0,0,0);\
    acc[3][3] = __builtin_amdgcn_mfma_f32_16x16x32_bf16(Hu[3], pf3, acc[3][3],0,0,0);\
    __builtin_amdgcn_s_setprio(0);                                              \
  }

__global__ __launch_bounds__(256, 2) void k_attn(
    const short* __restrict__ hAg, const float* __restrict__ el_t,
    const float* __restrict__ er_t, const float* __restrict__ prior,
    const int* __restrict__ mask, const float* __restrict__ esp,
    float* __restrict__ out) {
  const int bid = blockIdx.x;
  const int b  = bid & 7;           // XCD = bid % 8
  const int hp = (bid >> 3) & 1;    // head half
  const int it = bid >> 4;          // 0..15 (64-row tiles)
  const int t  = threadIdx.x;       // 256 threads = 4 waves
  const int h  = hp * 4 + (t >> 6); // wave = head
  const int l  = t & 63;
  const int lr = l & 15, lk = l >> 4;
  const int i0 = it * 64;
  const size_t bn = (size_t)b * N_;
  const float es = esp[0] * LOG2E;

  __shared__ short cbuf[2][16384];  // 2 x (64 rows x 256 cols) bf16 = 64 KB

  // staging geometry: thread -> row r = t>>2 (0..63), col quarter sub = t&3
  const int r    = t >> 2;
  const int sub  = t & 3;
  const int rbase = r * 256;
  const int rsw  = r & 7;
  const int sgrp = sub * 8;         // group base within row (8 groups/thread)
  const float* rowp = prior + (bn + i0 + r) * (size_t)N_ + sub * 64;
  const int*   rowm = mask  + (bn + i0 + r) * (size_t)N_ + sub * 64;
  f32x4 sp0, sp1; i32x4 sm0, sm1;

  const float* elh = el_t + h * BN_ + bn + i0;
  const float el0 = elh[lr], el1 = elh[16 + lr], el2 = elh[32 + lr], el3 = elh[48 + lr];
  const float* erp = er_t + h * BN_ + bn + lk * 8;
  const short* hW  = hAg + (size_t)(b * 8 + h) * 65536 + l * 8;
  const int xsw = lr & 7;

  bf16x8 HA[4], HB[4], cA[4], cB[4];
  f32x4 eA0, eA1, eB0, eB1;
  f32x4 acc[4][4] = {};
  f32x4 accS[4] = {};
  bf16x8 ones;
#pragma unroll
  for (int e = 0; e < 8; e++) ones[e] = (short)0x3F80;

  // ---- prologue: stage chunk 0 (8 groups/thread), prefetch h/er steps 0,1 ----
#pragma unroll
  for (int g = 0; g < 8; g++) {
    SLOAD(0, g);
    SWRITE(&cbuf[0][0], g);
  }
  PREF_G(0, HA, eA0, eA1);
  PREF_G(1, HB, eB0, eB1);
  __syncthreads();
  PREF_C4(&cbuf[0][0], 0, cA);
  PREF_C4(&cbuf[0][0], 1, cB);

  for (int ch = 0; ch < 4; ++ch) {
    const int s0 = ch * 8;
    const short* cbc = &cbuf[ch & 1][0];
    short*       cbn = &cbuf[(ch + 1) & 1][0];
    const bool stg = (ch < 3);
    // js = 0 (A)
    if (stg) { SLOAD(ch + 1, 0); }
    COMP4(HA, cA, eA0, eA1);
    PREF_G(s0 + 2, HA, eA0, eA1);  PREF_C4(cbc, 2, cA);
    // js = 1 (B)
    if (stg) { SWRITE(cbn, 0); SLOAD(ch + 1, 1); }
    COMP4(HB, cB, eB0, eB1);
    PREF_G(s0 + 3, HB, eB0, eB1);  PREF_C4(cbc, 3, cB);
    // js = 2 (A)
    if (stg) { SWRITE(cbn, 1); SLOAD(ch + 1, 2); }
    COMP4(HA, cA, eA0, eA1);
    PREF_G(s0 + 4, HA, eA0, eA1);  PREF_C4(cbc, 4, cA);
    // js = 3 (B)
    if (stg) { SWRITE(cbn, 2); SLOAD(ch + 1, 3); }
    COMP4(HB, cB, eB0, eB1);
    PREF_G(s0 + 5, HB, eB0, eB1);  PREF_C4(cbc, 5, cB);
    // js = 4 (A)
    if (stg) { SWRITE(cbn, 3); SLOAD(ch + 1, 4); }
    COMP4(HA, cA, eA0, eA1);
    PREF_G(s0 + 6, HA, eA0, eA1);  PREF_C4(cbc, 6, cA);
    // js = 5 (B)
    if (stg) { SWRITE(cbn, 4); SLOAD(ch + 1, 5); }
    COMP4(HB, cB, eB0, eB1);
    PREF_G(s0 + 7, HB, eB0, eB1);  PREF_C4(cbc, 7, cB);
    // js = 6 (A) — no c-prefetch (next chunk's buffer not published yet)
    if (stg) { SWRITE(cbn, 5); SLOAD(ch + 1, 6); }
    COMP4(HA, cA, eA0, eA1);
    { const int sn_ = (s0 + 8 > 31) ? 31 : s0 + 8; PREF_G(sn_, HA, eA0, eA1); }
    // js = 7 (B)
    if (stg) { SWRITE(cbn, 6); SLOAD(ch + 1, 7); }
    COMP4(HB, cB, eB0, eB1);
    { const int sn_ = (s0 + 9 > 31) ? 31 : s0 + 9; PREF_G(sn_, HB, eB0, eB1); }
    if (stg) {
      SWRITE(cbn, 7);
      __syncthreads();               // publish chunk ch+1
      PREF_C4(cbn, 0, cA);
      PREF_C4(cbn, 1, cB);
    }
  }

#pragma unroll
  for (int fi = 0; fi < 4; fi++) {
    const float inv = 1.0f / accS[fi][0];
    const size_t row = bn + i0 + fi * 16 + lr;
#pragma unroll
    for (int ff = 0; ff < 4; ff++) {
      f32x4 v = acc[ff][fi];
      v[0] *= inv; v[1] *= inv; v[2] *= inv; v[3] *= inv;
      *(f32x4*)(out + row * HF_ + h * 64 + ff * 16 + lk * 4) = v;
    }
  }
}

extern "C" void kernel_launch(void* const* d_in, const int* in_sizes, int n_in,
                              void* d_out, int out_size, void* d_ws, size_t ws_size,
                              hipStream_t stream) {
  const float* x     = (const float*)d_in[0];
  const int*   adj   = (const int*)  d_in[1];
  const float* prior = (const float*)d_in[2];
  const float* W     = (const float*)d_in[3];
  const float* aL    = (const float*)d_in[4];
  const float* aR    = (const float*)d_in[5];
  const float* es    = (const float*)d_in[6];
  float* out = (float*)d_out;

  char* ws = (char*)d_ws;
  short* hAg  = (short*)ws;                                 //  8 MB
  short* xb   = (short*)(ws + 8u  * 1024 * 1024);           //  4 MB
  short* Wt   = (short*)(ws + 12u * 1024 * 1024);           // 256 KB
  float* el_t = (float*)(ws + 12u * 1024 * 1024 + 262144);  // 256 KB
  float* er_t = (float*)(ws + 12u * 1024 * 1024 + 524288);  // 256 KB

  hipLaunchKernelGGL(k_cvt, dim3(1536), dim3(256), 0, stream, x, W, xb, Wt);
  hipLaunchKernelGGL(k_h,   dim3(128, 8), dim3(256), 0, stream,
                     Wt, xb, aL, aR, hAg, el_t, er_t);
  hipLaunchKernelGGL(k_attn, dim3(256), dim3(256), 0, stream,
                     hAg, el_t, er_t, prior, adj, es, out);
}

// Round 11
// 67.290 us; speedup vs baseline: 1.0724x; 1.0384x over previous
//
#include <hip/hip_runtime.h>
#include <hip/hip_bf16.h>

#define B_ 8
#define N_ 1024
#define FIN_ 256
#define H_ 8
#define F_ 64
#define HF_ 512
#define BN_ 8192
#define LOG2E 1.4426950408889634f

using bf16x8 = __attribute__((ext_vector_type(8))) short;
using f32x4  = __attribute__((ext_vector_type(4))) float;
using i32x4  = __attribute__((ext_vector_type(4))) int;

__device__ __forceinline__ short f2bf(float x) {
  __hip_bfloat16 b = __float2bfloat16(x);
  return *reinterpret_cast<short*>(&b);
}
__device__ __forceinline__ float bf2f(short s) {
  union { unsigned u; float f; } v;
  v.u = ((unsigned)(unsigned short)s) << 16;
  return v.f;
}
__device__ __forceinline__ bf16x8 cvtCE(f32x4 pa, f32x4 pb, i32x4 ma, i32x4 mb, float es) {
  bf16x8 o;
#pragma unroll
  for (int e = 0; e < 4; e++) {
    o[e]     = f2bf(ma[e] != 0 ? es * pa[e] : -1e30f);
    o[e + 4] = f2bf(mb[e] != 0 ? es * pb[e] : -1e30f);
  }
  return o;
}

// K0: xb = bf16(x) (blocks 0..1023); Wt[f][c] = bf16(W[c][f]) (blocks 1024..1535)
__global__ __launch_bounds__(256) void k_cvt(
    const float* __restrict__ x, const float* __restrict__ W,
    short* __restrict__ xb, short* __restrict__ Wt) {
  const int bid = blockIdx.x;
  if (bid < 1024) {
    const int idx = (bid * 256 + threadIdx.x) * 8;
    f32x4 a = *(const f32x4*)(x + idx);
    f32x4 b = *(const f32x4*)(x + idx + 4);
    bf16x8 o;
    o[0]=f2bf(a[0]); o[1]=f2bf(a[1]); o[2]=f2bf(a[2]); o[3]=f2bf(a[3]);
    o[4]=f2bf(b[0]); o[5]=f2bf(b[1]); o[6]=f2bf(b[2]); o[7]=f2bf(b[3]);
    *(bf16x8*)(xb + idx) = o;
  } else {
    const int idx = (bid - 1024) * 256 + threadIdx.x;
    const int f = idx >> 8, c = idx & 255;
    Wt[f * FIN_ + c] = f2bf(W[c * HF_ + f]);
  }
}

// K_pre: cmat = bf16(mask ? es*log2e*prior : -1e30) in PV-B-FRAGMENT order:
// cmat[((b*32+it)*32+s)*1024 + (i>=16)*512 + (((j>>3)&3)*16 + (i&15))*8 + (j&7)]
//   where i local to 32-row tile, j = s*32 + ...
__global__ __launch_bounds__(256) void k_pre(
    const float* __restrict__ prior, const int* __restrict__ mask,
    const float* __restrict__ esp, short* __restrict__ cmat) {
  const int b  = blockIdx.x & 7;
  const int it = blockIdx.x >> 3;   // 0..31
  const int t  = threadIdx.x;
  const int i  = t >> 3;            // 0..31 (row within tile)
  const int jb = (t & 7) * 8;       // 0..56
  const float es = esp[0] * LOG2E;
  const size_t rowbase = ((size_t)b * N_ + it * 32 + i) * N_;
  short* cmt = cmat + (size_t)(b * 32 + it) * 32768
             + (i >> 4) * 512 + (i & 15) * 8;
#pragma unroll
  for (int jt = 0; jt < 16; jt++) {
    const int j = jt * 64 + jb;
    f32x4 p0 = *(const f32x4*)(prior + rowbase + j);
    f32x4 p1 = *(const f32x4*)(prior + rowbase + j + 4);
    i32x4 m0 = *(const i32x4*)(mask + rowbase + j);
    i32x4 m1 = *(const i32x4*)(mask + rowbase + j + 4);
    *(bf16x8*)(cmt + (j >> 5) * 1024 + ((j >> 3) & 3) * 128) =
        cvtCE(p0, p1, m0, m1, es);
  }
}

// K1: h = x@W per-head 64f x 64n tile, fused el/er epilogue; writes hA in
// MFMA-A-fragment order via LDS transpose (j local to b):
// hAg[((b8h*32+js)*4+ff)*512 + l*8 + e] = h[h*64+ff*16+(l&15)][js*32+(l>>4)*8+e]
__global__ __launch_bounds__(256) void k_h(
    const short* __restrict__ Wt, const short* __restrict__ xb,
    const float* __restrict__ aL, const float* __restrict__ aR,
    short* __restrict__ hAg, float* __restrict__ el_t, float* __restrict__ er_t) {
  const int nt = blockIdx.x;
  const int h  = blockIdx.y;
  const int w  = threadIdx.x >> 6;
  const int l  = threadIdx.x & 63;
  const int lr = l & 15, lk = l >> 4;
  const int n0 = nt * 64;
  const int fbase = h * 64 + w * 16;

  f32x4 acc[4] = {};
  const short* arow = Wt + (fbase + lr) * FIN_ + lk * 8;

#pragma unroll
  for (int k0 = 0; k0 < FIN_; k0 += 32) {
    bf16x8 a = *(const bf16x8*)(arow + k0);
#pragma unroll
    for (int nf = 0; nf < 4; nf++) {
      bf16x8 bb = *(const bf16x8*)(xb + (size_t)(n0 + nf * 16 + lr) * FIN_ + k0 + lk * 8);
      acc[nf] = __builtin_amdgcn_mfma_f32_16x16x32_bf16(a, bb, acc[nf], 0, 0, 0);
    }
  }

  __shared__ short sT[64][72];
  __shared__ float sEl[4][64], sEr[4][64];
  float al[4], ar[4];
#pragma unroll
  for (int r = 0; r < 4; r++) {
    const int fl = w * 16 + lk * 4 + r;
    al[r] = aL[h * F_ + fl];
    ar[r] = aR[h * F_ + fl];
  }
#pragma unroll
  for (int nf = 0; nf < 4; nf++) {
    const int nl = nf * 16 + lr;
#pragma unroll
    for (int r = 0; r < 4; r++)
      sT[w * 16 + lk * 4 + r][nl] = f2bf(acc[nf][r]);
    float pl = acc[nf][0]*al[0] + acc[nf][1]*al[1] + acc[nf][2]*al[2] + acc[nf][3]*al[3];
    float pr = acc[nf][0]*ar[0] + acc[nf][1]*ar[1] + acc[nf][2]*ar[2] + acc[nf][3]*ar[3];
    pl += __shfl_xor(pl, 16); pl += __shfl_xor(pl, 32);
    pr += __shfl_xor(pr, 16); pr += __shfl_xor(pr, 32);
    if (lk == 0) { sEl[w][nl] = pl; sEr[w][nl] = pr; }
  }
  __syncthreads();
  if (threadIdx.x < 64) {
    const int n = threadIdx.x;
    el_t[h * BN_ + n0 + n] = (sEl[0][n] + sEl[1][n] + sEl[2][n] + sEl[3][n]) * LOG2E;
    er_t[h * BN_ + n0 + n] = (sEr[0][n] + sEr[1][n] + sEr[2][n] + sEr[3][n]) * LOG2E;
  }
  const int b8h = (nt >> 4) * 8 + h;
  const int jb  = (nt & 15) * 2;
#pragma unroll
  for (int gi = 0; gi < 2; gi++) {
    const int g   = threadIdx.x * 2 + gi;
    const int jsl = g >> 8, ff = (g >> 6) & 3, gl = g & 63;
    const int glr = gl & 15, glk = gl >> 4;
    bf16x8 v = *(const bf16x8*)(&sT[ff * 16 + glr][jsl * 32 + glk * 8]);
    *(bf16x8*)(hAg + (((size_t)b8h * 32 + jb + jsl) * 4 + ff) * 512 + gl * 8) = v;
  }
}

// K2 v11: pure-register core. No LDS, no barriers. Per step: 2 cm frag loads
// (lane-linear bf16x8 from pre-swizzled cmat), 4 h frags, 2 er — all L2-hot
// (per-XCD working set ~3 MB < 4 MB L2 since the f32 stream is gone).
// Depth-4 software pipeline (A/B/C/D). Block = 256 thr = 4 heads; 2 i-frags
// per wave; grid = 8b x 2hp x 32it = 512 = 2 blocks/CU.
#define PREFX(sn, Hd, E0d, E1d, Cd)                                   \
  {                                                                   \
    const short* hs_ = hW + (size_t)(sn) * 2048;                      \
    Hd[0] = *(const bf16x8*)(hs_);                                    \
    Hd[1] = *(const bf16x8*)(hs_ + 512);                              \
    Hd[2] = *(const bf16x8*)(hs_ + 1024);                             \
    Hd[3] = *(const bf16x8*)(hs_ + 1536);                             \
    E0d   = *(const f32x4*)(erp + (sn) * 32);                         \
    E1d   = *(const f32x4*)(erp + (sn) * 32 + 4);                     \
    Cd[0] = *(const bf16x8*)(cmW + (size_t)(sn) * 1024);              \
    Cd[1] = *(const bf16x8*)(cmW + (size_t)(sn) * 1024 + 512);        \
  }

#define COMP2(Hu, Cu, E0u, E1u)                                                \
  {                                                                            \
    bf16x8 pfA, pfB;                                                           \
    _Pragma("unroll")                                                          \
    for (int q = 0; q < 4; q++) {                                              \
      const float e0 = E0u[q], e1 = E1u[q];                                    \
      float sA  = el0 + e0, sA2 = el0 + e1;                                    \
      float sB  = el1 + e0, sB2 = el1 + e1;                                    \
      float vA  = fmaf(0.6f, sA,  bf2f(Cu[0][q]));                             \
      vA  = fmaf(0.4f, fabsf(sA),  vA);                                        \
      float vA2 = fmaf(0.6f, sA2, bf2f(Cu[0][q + 4]));                         \
      vA2 = fmaf(0.4f, fabsf(sA2), vA2);                                       \
      float vB  = fmaf(0.6f, sB,  bf2f(Cu[1][q]));                             \
      vB  = fmaf(0.4f, fabsf(sB),  vB);                                        \
      float vB2 = fmaf(0.6f, sB2, bf2f(Cu[1][q + 4]));                         \
      vB2 = fmaf(0.4f, fabsf(sB2), vB2);                                       \
      float x1_, x2_, x3_, x4_;                                                \
      asm("v_exp_f32 %0, %1" : "=v"(x1_) : "v"(vA));                           \
      asm("v_exp_f32 %0, %1" : "=v"(x2_) : "v"(vA2));                          \
      asm("v_exp_f32 %0, %1" : "=v"(x3_) : "v"(vB));                           \
      asm("v_exp_f32 %0, %1" : "=v"(x4_) : "v"(vB2));                          \
      pfA[q] = f2bf(x1_); pfA[q + 4] = f2bf(x2_);                              \
      pfB[q] = f2bf(x3_); pfB[q + 4] = f2bf(x4_);                              \
    }                                                                          \
    __builtin_amdgcn_s_setprio(1);                                             \
    accSA   = __builtin_amdgcn_mfma_f32_16x16x32_bf16(ones, pfA, accSA, 0,0,0);\
    accSB   = __builtin_amdgcn_mfma_f32_16x16x32_bf16(ones, pfB, accSB, 0,0,0);\
    accA[0] = __builtin_amdgcn_mfma_f32_16x16x32_bf16(Hu[0], pfA, accA[0],0,0,0);\
    accB[0] = __builtin_amdgcn_mfma_f32_16x16x32_bf16(Hu[0], pfB, accB[0],0,0,0);\
    accA[1] = __builtin_amdgcn_mfma_f32_16x16x32_bf16(Hu[1], pfA, accA[1],0,0,0);\
    accB[1] = __builtin_amdgcn_mfma_f32_16x16x32_bf16(Hu[1], pfB, accB[1],0,0,0);\
    accA[2] = __builtin_amdgcn_mfma_f32_16x16x32_bf16(Hu[2], pfA, accA[2],0,0,0);\
    accB[2] = __builtin_amdgcn_mfma_f32_16x16x32_bf16(Hu[2], pfB, accB[2],0,0,0);\
    accA[3] = __builtin_amdgcn_mfma_f32_16x16x32_bf16(Hu[3], pfA, accA[3],0,0,0);\
    accB[3] = __builtin_amdgcn_mfma_f32_16x16x32_bf16(Hu[3], pfB, accB[3],0,0,0);\
    __builtin_amdgcn_s_setprio(0);                                             \
  }

__global__ __launch_bounds__(256, 2) void k_attn(
    const short* __restrict__ hAg, const float* __restrict__ el_t,
    const float* __restrict__ er_t, const short* __restrict__ cmat,
    float* __restrict__ out) {
  const int bid = blockIdx.x;
  const int b  = bid & 7;           // XCD = bid % 8
  const int hp = (bid >> 3) & 1;    // head half
  const int it = bid >> 4;          // 0..31
  const int t  = threadIdx.x;       // 256 threads = 4 waves
  const int h  = hp * 4 + (t >> 6); // wave = head
  const int l  = t & 63;
  const int lr = l & 15, lk = l >> 4;
  const int i0 = it * 32;
  const size_t bn = (size_t)b * N_;

  const float el0 = el_t[h * BN_ + bn + i0 + lr];
  const float el1 = el_t[h * BN_ + bn + i0 + 16 + lr];
  const float* erp = er_t + h * BN_ + bn + lk * 8;
  const short* hW  = hAg + (size_t)(b * 8 + h) * 65536 + l * 8;
  const short* cmW = cmat + (size_t)(b * 32 + it) * 32768 + l * 8;

  bf16x8 HA[4], HB[4], HC[4], HD[4];
  bf16x8 cA[2], cB[2], cC[2], cD[2];
  f32x4 eA0, eA1, eB0, eB1, eC0, eC1, eD0, eD1;
  f32x4 accA[4] = {}, accB[4] = {};
  f32x4 accSA = {}, accSB = {};
  bf16x8 ones;
#pragma unroll
  for (int e = 0; e < 8; e++) ones[e] = (short)0x3F80;

  PREFX(0, HA, eA0, eA1, cA);
  PREFX(1, HB, eB0, eB1, cB);
  PREFX(2, HC, eC0, eC1, cC);
  PREFX(3, HD, eD0, eD1, cD);

  for (int s = 0; s < 32; s += 4) {  // branchless: tail prefetches read pads
    COMP2(HA, cA, eA0, eA1);  PREFX(s + 4, HA, eA0, eA1, cA);
    COMP2(HB, cB, eB0, eB1);  PREFX(s + 5, HB, eB0, eB1, cB);
    COMP2(HC, cC, eC0, eC1);  PREFX(s + 6, HC, eC0, eC1, cC);
    COMP2(HD, cD, eD0, eD1);  PREFX(s + 7, HD, eD0, eD1, cD);
  }

  const float invA = 1.0f / accSA[0];
  const float invB = 1.0f / accSB[0];
  const size_t rowA = bn + i0 + lr;
  const size_t rowB = rowA + 16;
#pragma unroll
  for (int ff = 0; ff < 4; ff++) {
    f32x4 va = accA[ff], vb = accB[ff];
    va[0]*=invA; va[1]*=invA; va[2]*=invA; va[3]*=invA;
    vb[0]*=invB; vb[1]*=invB; vb[2]*=invB; vb[3]*=invB;
    *(f32x4*)(out + rowA * HF_ + h * 64 + ff * 16 + lk * 4) = va;
    *(f32x4*)(out + rowB * HF_ + h * 64 + ff * 16 + lk * 4) = vb;
  }
}

extern "C" void kernel_launch(void* const* d_in, const int* in_sizes, int n_in,
                              void* d_out, int out_size, void* d_ws, size_t ws_size,
                              hipStream_t stream) {
  const float* x     = (const float*)d_in[0];
  const int*   adj   = (const int*)  d_in[1];
  const float* prior = (const float*)d_in[2];
  const float* W     = (const float*)d_in[3];
  const float* aL    = (const float*)d_in[4];
  const float* aR    = (const float*)d_in[5];
  const float* es    = (const float*)d_in[6];
  float* out = (float*)d_out;

  char* ws = (char*)d_ws;
  short* hAg  = (short*)ws;                                 //  0 MB,  8 MB
  short* xb   = (short*)(ws + 8u  * 1024 * 1024);           //  8 MB,  4 MB
  short* Wt   = (short*)(ws + 12u * 1024 * 1024);           // 12 MB, 256 KB
  float* el_t = (float*)(ws + 12u * 1024 * 1024 + 262144);  // 256 KB
  float* er_t = (float*)(ws + 12u * 1024 * 1024 + 524288);  // 256 KB
  short* cmat = (short*)(ws + 13u * 1024 * 1024);           // 13 MB, 16 MB (+pad)

  hipLaunchKernelGGL(k_cvt, dim3(1536), dim3(256), 0, stream, x, W, xb, Wt);
  hipLaunchKernelGGL(k_pre, dim3(256), dim3(256), 0, stream, prior, adj, es, cmat);
  hipLaunchKernelGGL(k_h,   dim3(128, 8), dim3(256), 0, stream,
                     Wt, xb, aL, aR, hAg, el_t, er_t);
  hipLaunchKernelGGL(k_attn, dim3(512), dim3(256), 0, stream,
                     hAg, el_t, er_t, cmat, out);
}

// Round 12
// 64.546 us; speedup vs baseline: 1.1180x; 1.0425x over previous
//
#include <hip/hip_runtime.h>
#include <hip/hip_bf16.h>

#define B_ 8
#define N_ 1024
#define FIN_ 256
#define H_ 8
#define F_ 64
#define HF_ 512
#define BN_ 8192
#define LOG2E 1.4426950408889634f

using bf16x8 = __attribute__((ext_vector_type(8))) short;
using f32x4  = __attribute__((ext_vector_type(4))) float;
using i32x4  = __attribute__((ext_vector_type(4))) int;

__device__ __forceinline__ short f2bf(float x) {
  __hip_bfloat16 b = __float2bfloat16(x);
  return *reinterpret_cast<short*>(&b);
}
__device__ __forceinline__ float bf2f(short s) {
  union { unsigned u; float f; } v;
  v.u = ((unsigned)(unsigned short)s) << 16;
  return v.f;
}
__device__ __forceinline__ bf16x8 cvtCE(f32x4 pa, f32x4 pb, i32x4 ma, i32x4 mb, float es) {
  bf16x8 o;
#pragma unroll
  for (int e = 0; e < 4; e++) {
    o[e]     = f2bf(ma[e] != 0 ? es * pa[e] : -1e30f);
    o[e + 4] = f2bf(mb[e] != 0 ? es * pb[e] : -1e30f);
  }
  return o;
}

// K_prep: fused (a) cmat build with LDS transpose -> fully coalesced global
// writes in PV-B-fragment order, (b) xb/Wt bf16 conversion (old k_cvt).
// cmat[((b*32+it)*32+s)*1024 + frag*512 + l*8 + e] = c[i][j],
//   i = it*32 + frag*16 + (l&15), j = s*32 + (l>>4)*8 + e,
//   c = mask ? es*log2e*prior : -1e30.
__global__ __launch_bounds__(256) void k_prep(
    const float* __restrict__ x, const float* __restrict__ W,
    const float* __restrict__ prior, const int* __restrict__ mask,
    const float* __restrict__ esp,
    short* __restrict__ xb, short* __restrict__ Wt, short* __restrict__ cmat) {
  const int bid = blockIdx.x;
  const int t   = threadIdx.x;
  if (bid >= 256) {                     // ---- cvt role (old k_cvt) ----
    const int cid = bid - 256;
    if (cid < 1024) {
      const int idx = (cid * 256 + t) * 8;
      f32x4 a = *(const f32x4*)(x + idx);
      f32x4 b = *(const f32x4*)(x + idx + 4);
      bf16x8 o;
      o[0]=f2bf(a[0]); o[1]=f2bf(a[1]); o[2]=f2bf(a[2]); o[3]=f2bf(a[3]);
      o[4]=f2bf(b[0]); o[5]=f2bf(b[1]); o[6]=f2bf(b[2]); o[7]=f2bf(b[3]);
      *(bf16x8*)(xb + idx) = o;
    } else {
      const int idx = (cid - 1024) * 256 + t;
      const int f = idx >> 8, c = idx & 255;
      Wt[f * FIN_ + c] = f2bf(W[c * HF_ + f]);
    }
    return;
  }
  // ---- pre role: one (b, it) 32x1024 tile ----
  __shared__ short stile[32768];        // 64 KB
  const int b  = bid & 7;
  const int it = bid >> 3;
  const float es = esp[0] * LOG2E;
  const int r  = t >> 3;                // 0..31 (row in tile)
  const int jb = (t & 7) * 8;
  const int frag = r >> 4, rl = r & 15;
  const size_t rowbase = ((size_t)b * N_ + it * 32 + r) * (size_t)N_;
#pragma unroll
  for (int jt = 0; jt < 16; jt++) {
    const int j = jt * 64 + jb;
    f32x4 p0 = *(const f32x4*)(prior + rowbase + j);
    f32x4 p1 = *(const f32x4*)(prior + rowbase + j + 4);
    i32x4 m0 = *(const i32x4*)(mask + rowbase + j);
    i32x4 m1 = *(const i32x4*)(mask + rowbase + j + 4);
    const int s = j >> 5;
    const int l = ((j >> 3) & 3) * 16 + rl;
    const int lsw = l ^ (2 * (l >> 4)) ^ ((s & 1) << 3);   // bank swizzle
    *(bf16x8*)(&stile[s * 1024 + frag * 512 + lsw * 8]) = cvtCE(p0, p1, m0, m1, es);
  }
  __syncthreads();
  short* cmt = cmat + (size_t)(b * 32 + it) * 32768;
#pragma unroll
  for (int k = 0; k < 16; k++) {
    const int g   = k * 2048 + t * 8;   // linear short offset in tile
    const int s   = g >> 10;
    const int rem = g & 1023;
    const int fr  = rem >> 9;
    const int l   = (rem >> 3) & 63;
    const int lsw = l ^ (2 * (l >> 4)) ^ ((s & 1) << 3);
    bf16x8 v = *(const bf16x8*)(&stile[s * 1024 + fr * 512 + lsw * 8]);
    *(bf16x8*)(cmt + g) = v;            // wave-contiguous 1KB stores
  }
}

// K1: h = x@W per-head 64f x 64n tile, fused el/er epilogue; writes hA in
// MFMA-A-fragment order via LDS transpose (j local to b):
// hAg[((b8h*32+js)*4+ff)*512 + l*8 + e] = h[h*64+ff*16+(l&15)][js*32+(l>>4)*8+e]
__global__ __launch_bounds__(256) void k_h(
    const short* __restrict__ Wt, const short* __restrict__ xb,
    const float* __restrict__ aL, const float* __restrict__ aR,
    short* __restrict__ hAg, float* __restrict__ el_t, float* __restrict__ er_t) {
  const int nt = blockIdx.x;
  const int h  = blockIdx.y;
  const int w  = threadIdx.x >> 6;
  const int l  = threadIdx.x & 63;
  const int lr = l & 15, lk = l >> 4;
  const int n0 = nt * 64;
  const int fbase = h * 64 + w * 16;

  f32x4 acc[4] = {};
  const short* arow = Wt + (fbase + lr) * FIN_ + lk * 8;

#pragma unroll
  for (int k0 = 0; k0 < FIN_; k0 += 32) {
    bf16x8 a = *(const bf16x8*)(arow + k0);
#pragma unroll
    for (int nf = 0; nf < 4; nf++) {
      bf16x8 bb = *(const bf16x8*)(xb + (size_t)(n0 + nf * 16 + lr) * FIN_ + k0 + lk * 8);
      acc[nf] = __builtin_amdgcn_mfma_f32_16x16x32_bf16(a, bb, acc[nf], 0, 0, 0);
    }
  }

  __shared__ short sT[64][72];
  __shared__ float sEl[4][64], sEr[4][64];
  float al[4], ar[4];
#pragma unroll
  for (int r = 0; r < 4; r++) {
    const int fl = w * 16 + lk * 4 + r;
    al[r] = aL[h * F_ + fl];
    ar[r] = aR[h * F_ + fl];
  }
#pragma unroll
  for (int nf = 0; nf < 4; nf++) {
    const int nl = nf * 16 + lr;
#pragma unroll
    for (int r = 0; r < 4; r++)
      sT[w * 16 + lk * 4 + r][nl] = f2bf(acc[nf][r]);
    float pl = acc[nf][0]*al[0] + acc[nf][1]*al[1] + acc[nf][2]*al[2] + acc[nf][3]*al[3];
    float pr = acc[nf][0]*ar[0] + acc[nf][1]*ar[1] + acc[nf][2]*ar[2] + acc[nf][3]*ar[3];
    pl += __shfl_xor(pl, 16); pl += __shfl_xor(pl, 32);
    pr += __shfl_xor(pr, 16); pr += __shfl_xor(pr, 32);
    if (lk == 0) { sEl[w][nl] = pl; sEr[w][nl] = pr; }
  }
  __syncthreads();
  if (threadIdx.x < 64) {
    const int n = threadIdx.x;
    el_t[h * BN_ + n0 + n] = (sEl[0][n] + sEl[1][n] + sEl[2][n] + sEl[3][n]) * LOG2E;
    er_t[h * BN_ + n0 + n] = (sEr[0][n] + sEr[1][n] + sEr[2][n] + sEr[3][n]) * LOG2E;
  }
  const int b8h = (nt >> 4) * 8 + h;
  const int jb  = (nt & 15) * 2;
#pragma unroll
  for (int gi = 0; gi < 2; gi++) {
    const int g   = threadIdx.x * 2 + gi;
    const int jsl = g >> 8, ff = (g >> 6) & 3, gl = g & 63;
    const int glr = gl & 15, glk = gl >> 4;
    bf16x8 v = *(const bf16x8*)(&sT[ff * 16 + glr][jsl * 32 + glk * 8]);
    *(bf16x8*)(hAg + (((size_t)b8h * 32 + jb + jsl) * 4 + ff) * 512 + gl * 8) = v;
  }
}

// K2 v11 (UNCHANGED): pure-register core, no LDS/barriers, depth-4 pipeline.
#define PREFX(sn, Hd, E0d, E1d, Cd)                                   \
  {                                                                   \
    const short* hs_ = hW + (size_t)(sn) * 2048;                      \
    Hd[0] = *(const bf16x8*)(hs_);                                    \
    Hd[1] = *(const bf16x8*)(hs_ + 512);                              \
    Hd[2] = *(const bf16x8*)(hs_ + 1024);                             \
    Hd[3] = *(const bf16x8*)(hs_ + 1536);                             \
    E0d   = *(const f32x4*)(erp + (sn) * 32);                         \
    E1d   = *(const f32x4*)(erp + (sn) * 32 + 4);                     \
    Cd[0] = *(const bf16x8*)(cmW + (size_t)(sn) * 1024);              \
    Cd[1] = *(const bf16x8*)(cmW + (size_t)(sn) * 1024 + 512);        \
  }

#define COMP2(Hu, Cu, E0u, E1u)                                                \
  {                                                                            \
    bf16x8 pfA, pfB;                                                           \
    _Pragma("unroll")                                                          \
    for (int q = 0; q < 4; q++) {                                              \
      const float e0 = E0u[q], e1 = E1u[q];                                    \
      float sA  = el0 + e0, sA2 = el0 + e1;                                    \
      float sB  = el1 + e0, sB2 = el1 + e1;                                    \
      float vA  = fmaf(0.6f, sA,  bf2f(Cu[0][q]));                             \
      vA  = fmaf(0.4f, fabsf(sA),  vA);                                        \
      float vA2 = fmaf(0.6f, sA2, bf2f(Cu[0][q + 4]));                         \
      vA2 = fmaf(0.4f, fabsf(sA2), vA2);                                       \
      float vB  = fmaf(0.6f, sB,  bf2f(Cu[1][q]));                             \
      vB  = fmaf(0.4f, fabsf(sB),  vB);                                        \
      float vB2 = fmaf(0.6f, sB2, bf2f(Cu[1][q + 4]));                         \
      vB2 = fmaf(0.4f, fabsf(sB2), vB2);                                       \
      float x1_, x2_, x3_, x4_;                                                \
      asm("v_exp_f32 %0, %1" : "=v"(x1_) : "v"(vA));                           \
      asm("v_exp_f32 %0, %1" : "=v"(x2_) : "v"(vA2));                          \
      asm("v_exp_f32 %0, %1" : "=v"(x3_) : "v"(vB));                           \
      asm("v_exp_f32 %0, %1" : "=v"(x4_) : "v"(vB2));                          \
      pfA[q] = f2bf(x1_); pfA[q + 4] = f2bf(x2_);                              \
      pfB[q] = f2bf(x3_); pfB[q + 4] = f2bf(x4_);                              \
    }                                                                          \
    __builtin_amdgcn_s_setprio(1);                                             \
    accSA   = __builtin_amdgcn_mfma_f32_16x16x32_bf16(ones, pfA, accSA, 0,0,0);\
    accSB   = __builtin_amdgcn_mfma_f32_16x16x32_bf16(ones, pfB, accSB, 0,0,0);\
    accA[0] = __builtin_amdgcn_mfma_f32_16x16x32_bf16(Hu[0], pfA, accA[0],0,0,0);\
    accB[0] = __builtin_amdgcn_mfma_f32_16x16x32_bf16(Hu[0], pfB, accB[0],0,0,0);\
    accA[1] = __builtin_amdgcn_mfma_f32_16x16x32_bf16(Hu[1], pfA, accA[1],0,0,0);\
    accB[1] = __builtin_amdgcn_mfma_f32_16x16x32_bf16(Hu[1], pfB, accB[1],0,0,0);\
    accA[2] = __builtin_amdgcn_mfma_f32_16x16x32_bf16(Hu[2], pfA, accA[2],0,0,0);\
    accB[2] = __builtin_amdgcn_mfma_f32_16x16x32_bf16(Hu[2], pfB, accB[2],0,0,0);\
    accA[3] = __builtin_amdgcn_mfma_f32_16x16x32_bf16(Hu[3], pfA, accA[3],0,0,0);\
    accB[3] = __builtin_amdgcn_mfma_f32_16x16x32_bf16(Hu[3], pfB, accB[3],0,0,0);\
    __builtin_amdgcn_s_setprio(0);                                             \
  }

__global__ __launch_bounds__(256, 2) void k_attn(
    const short* __restrict__ hAg, const float* __restrict__ el_t,
    const float* __restrict__ er_t, const short* __restrict__ cmat,
    float* __restrict__ out) {
  const int bid = blockIdx.x;
  const int b  = bid & 7;           // XCD = bid % 8
  const int hp = (bid >> 3) & 1;    // head half
  const int it = bid >> 4;          // 0..31
  const int t  = threadIdx.x;       // 256 threads = 4 waves
  const int h  = hp * 4 + (t >> 6); // wave = head
  const int l  = t & 63;
  const int lr = l & 15, lk = l >> 4;
  const int i0 = it * 32;
  const size_t bn = (size_t)b * N_;

  const float el0 = el_t[h * BN_ + bn + i0 + lr];
  const float el1 = el_t[h * BN_ + bn + i0 + 16 + lr];
  const float* erp = er_t + h * BN_ + bn + lk * 8;
  const short* hW  = hAg + (size_t)(b * 8 + h) * 65536 + l * 8;
  const short* cmW = cmat + (size_t)(b * 32 + it) * 32768 + l * 8;

  bf16x8 HA[4], HB[4], HC[4], HD[4];
  bf16x8 cA[2], cB[2], cC[2], cD[2];
  f32x4 eA0, eA1, eB0, eB1, eC0, eC1, eD0, eD1;
  f32x4 accA[4] = {}, accB[4] = {};
  f32x4 accSA = {}, accSB = {};
  bf16x8 ones;
#pragma unroll
  for (int e = 0; e < 8; e++) ones[e] = (short)0x3F80;

  PREFX(0, HA, eA0, eA1, cA);
  PREFX(1, HB, eB0, eB1, cB);
  PREFX(2, HC, eC0, eC1, cC);
  PREFX(3, HD, eD0, eD1, cD);

  for (int s = 0; s < 32; s += 4) {  // branchless: tail prefetches read pads
    COMP2(HA, cA, eA0, eA1);  PREFX(s + 4, HA, eA0, eA1, cA);
    COMP2(HB, cB, eB0, eB1);  PREFX(s + 5, HB, eB0, eB1, cB);
    COMP2(HC, cC, eC0, eC1);  PREFX(s + 6, HC, eC0, eC1, cC);
    COMP2(HD, cD, eD0, eD1);  PREFX(s + 7, HD, eD0, eD1, cD);
  }

  const float invA = 1.0f / accSA[0];
  const float invB = 1.0f / accSB[0];
  const size_t rowA = bn + i0 + lr;
  const size_t rowB = rowA + 16;
#pragma unroll
  for (int ff = 0; ff < 4; ff++) {
    f32x4 va = accA[ff], vb = accB[ff];
    va[0]*=invA; va[1]*=invA; va[2]*=invA; va[3]*=invA;
    vb[0]*=invB; vb[1]*=invB; vb[2]*=invB; vb[3]*=invB;
    *(f32x4*)(out + rowA * HF_ + h * 64 + ff * 16 + lk * 4) = va;
    *(f32x4*)(out + rowB * HF_ + h * 64 + ff * 16 + lk * 4) = vb;
  }
}

extern "C" void kernel_launch(void* const* d_in, const int* in_sizes, int n_in,
                              void* d_out, int out_size, void* d_ws, size_t ws_size,
                              hipStream_t stream) {
  const float* x     = (const float*)d_in[0];
  const int*   adj   = (const int*)  d_in[1];
  const float* prior = (const float*)d_in[2];
  const float* W     = (const float*)d_in[3];
  const float* aL    = (const float*)d_in[4];
  const float* aR    = (const float*)d_in[5];
  const float* es    = (const float*)d_in[6];
  float* out = (float*)d_out;

  char* ws = (char*)d_ws;
  short* hAg  = (short*)ws;                                 //  0 MB,  8 MB
  short* xb   = (short*)(ws + 8u  * 1024 * 1024);           //  8 MB,  4 MB
  short* Wt   = (short*)(ws + 12u * 1024 * 1024);           // 12 MB, 256 KB
  float* el_t = (float*)(ws + 12u * 1024 * 1024 + 262144);  // 256 KB
  float* er_t = (float*)(ws + 12u * 1024 * 1024 + 524288);  // 256 KB
  short* cmat = (short*)(ws + 13u * 1024 * 1024);           // 13 MB, 16 MB (+pad)

  hipLaunchKernelGGL(k_prep, dim3(1792), dim3(256), 0, stream,
                     x, W, prior, adj, es, xb, Wt, cmat);
  hipLaunchKernelGGL(k_h,   dim3(128, 8), dim3(256), 0, stream,
                     Wt, xb, aL, aR, hAg, el_t, er_t);
  hipLaunchKernelGGL(k_attn, dim3(512), dim3(256), 0, stream,
                     hAg, el_t, er_t, cmat, out);
}

// Round 13
// 64.510 us; speedup vs baseline: 1.1186x; 1.0006x over previous
//
#include <hip/hip_runtime.h>
#include <hip/hip_bf16.h>

#define B_ 8
#define N_ 1024
#define FIN_ 256
#define H_ 8
#define F_ 64
#define HF_ 512
#define BN_ 8192
#define LOG2E 1.4426950408889634f

using bf16x8 = __attribute__((ext_vector_type(8))) short;
using f32x4  = __attribute__((ext_vector_type(4))) float;
using i32x4  = __attribute__((ext_vector_type(4))) int;

__device__ __forceinline__ short f2bf(float x) {
  __hip_bfloat16 b = __float2bfloat16(x);
  return *reinterpret_cast<short*>(&b);
}
__device__ __forceinline__ float bf2f(short s) {
  union { unsigned u; float f; } v;
  v.u = ((unsigned)(unsigned short)s) << 16;
  return v.f;
}
__device__ __forceinline__ bf16x8 cvtCE(f32x4 pa, f32x4 pb, i32x4 ma, i32x4 mb, float es) {
  bf16x8 o;
#pragma unroll
  for (int e = 0; e < 4; e++) {
    o[e]     = f2bf(ma[e] != 0 ? es * pa[e] : -1e30f);
    o[e + 4] = f2bf(mb[e] != 0 ? es * pb[e] : -1e30f);
  }
  return o;
}

// K_prep: fused (a) cmat build with LDS transpose -> fully coalesced global
// writes in PV-B-fragment order, (b) xb/Wt bf16 conversion.
__global__ __launch_bounds__(256) void k_prep(
    const float* __restrict__ x, const float* __restrict__ W,
    const float* __restrict__ prior, const int* __restrict__ mask,
    const float* __restrict__ esp,
    short* __restrict__ xb, short* __restrict__ Wt, short* __restrict__ cmat) {
  const int bid = blockIdx.x;
  const int t   = threadIdx.x;
  if (bid >= 256) {                     // ---- cvt role ----
    const int cid = bid - 256;
    if (cid < 1024) {
      const int idx = (cid * 256 + t) * 8;
      f32x4 a = *(const f32x4*)(x + idx);
      f32x4 b = *(const f32x4*)(x + idx + 4);
      bf16x8 o;
      o[0]=f2bf(a[0]); o[1]=f2bf(a[1]); o[2]=f2bf(a[2]); o[3]=f2bf(a[3]);
      o[4]=f2bf(b[0]); o[5]=f2bf(b[1]); o[6]=f2bf(b[2]); o[7]=f2bf(b[3]);
      *(bf16x8*)(xb + idx) = o;
    } else {
      const int idx = (cid - 1024) * 256 + t;
      const int f = idx >> 8, c = idx & 255;
      Wt[f * FIN_ + c] = f2bf(W[c * HF_ + f]);
    }
    return;
  }
  // ---- pre role: one (b, it) 32x1024 tile ----
  __shared__ short stile[32768];        // 64 KB
  const int b  = bid & 7;
  const int it = bid >> 3;
  const float es = esp[0] * LOG2E;
  const int r  = t >> 3;                // 0..31
  const int jb = (t & 7) * 8;
  const int frag = r >> 4, rl = r & 15;
  const size_t rowbase = ((size_t)b * N_ + it * 32 + r) * (size_t)N_;
#pragma unroll
  for (int jt = 0; jt < 16; jt++) {
    const int j = jt * 64 + jb;
    f32x4 p0 = *(const f32x4*)(prior + rowbase + j);
    f32x4 p1 = *(const f32x4*)(prior + rowbase + j + 4);
    i32x4 m0 = *(const i32x4*)(mask + rowbase + j);
    i32x4 m1 = *(const i32x4*)(mask + rowbase + j + 4);
    const int s = j >> 5;
    const int l = ((j >> 3) & 3) * 16 + rl;
    const int lsw = l ^ (2 * (l >> 4)) ^ ((s & 1) << 3);   // bank swizzle
    *(bf16x8*)(&stile[s * 1024 + frag * 512 + lsw * 8]) = cvtCE(p0, p1, m0, m1, es);
  }
  __syncthreads();
  short* cmt = cmat + (size_t)(b * 32 + it) * 32768;
#pragma unroll
  for (int k = 0; k < 16; k++) {
    const int g   = k * 2048 + t * 8;
    const int s   = g >> 10;
    const int rem = g & 1023;
    const int fr  = rem >> 9;
    const int l   = (rem >> 3) & 63;
    const int lsw = l ^ (2 * (l >> 4)) ^ ((s & 1) << 3);
    bf16x8 v = *(const bf16x8*)(&stile[s * 1024 + fr * 512 + lsw * 8]);
    *(bf16x8*)(cmt + g) = v;            // wave-contiguous 1KB stores
  }
}

// K1: h = x@W per-head 64f x 64n tile, fused el/er epilogue; writes hA in
// MFMA-A-fragment order via LDS transpose (unchanged).
__global__ __launch_bounds__(256) void k_h(
    const short* __restrict__ Wt, const short* __restrict__ xb,
    const float* __restrict__ aL, const float* __restrict__ aR,
    short* __restrict__ hAg, float* __restrict__ el_t, float* __restrict__ er_t) {
  const int nt = blockIdx.x;
  const int h  = blockIdx.y;
  const int w  = threadIdx.x >> 6;
  const int l  = threadIdx.x & 63;
  const int lr = l & 15, lk = l >> 4;
  const int n0 = nt * 64;
  const int fbase = h * 64 + w * 16;

  f32x4 acc[4] = {};
  const short* arow = Wt + (fbase + lr) * FIN_ + lk * 8;

#pragma unroll
  for (int k0 = 0; k0 < FIN_; k0 += 32) {
    bf16x8 a = *(const bf16x8*)(arow + k0);
#pragma unroll
    for (int nf = 0; nf < 4; nf++) {
      bf16x8 bb = *(const bf16x8*)(xb + (size_t)(n0 + nf * 16 + lr) * FIN_ + k0 + lk * 8);
      acc[nf] = __builtin_amdgcn_mfma_f32_16x16x32_bf16(a, bb, acc[nf], 0, 0, 0);
    }
  }

  __shared__ short sT[64][72];
  __shared__ float sEl[4][64], sEr[4][64];
  float al[4], ar[4];
#pragma unroll
  for (int r = 0; r < 4; r++) {
    const int fl = w * 16 + lk * 4 + r;
    al[r] = aL[h * F_ + fl];
    ar[r] = aR[h * F_ + fl];
  }
#pragma unroll
  for (int nf = 0; nf < 4; nf++) {
    const int nl = nf * 16 + lr;
#pragma unroll
    for (int r = 0; r < 4; r++)
      sT[w * 16 + lk * 4 + r][nl] = f2bf(acc[nf][r]);
    float pl = acc[nf][0]*al[0] + acc[nf][1]*al[1] + acc[nf][2]*al[2] + acc[nf][3]*al[3];
    float pr = acc[nf][0]*ar[0] + acc[nf][1]*ar[1] + acc[nf][2]*ar[2] + acc[nf][3]*ar[3];
    pl += __shfl_xor(pl, 16); pl += __shfl_xor(pl, 32);
    pr += __shfl_xor(pr, 16); pr += __shfl_xor(pr, 32);
    if (lk == 0) { sEl[w][nl] = pl; sEr[w][nl] = pr; }
  }
  __syncthreads();
  if (threadIdx.x < 64) {
    const int n = threadIdx.x;
    el_t[h * BN_ + n0 + n] = (sEl[0][n] + sEl[1][n] + sEl[2][n] + sEl[3][n]) * LOG2E;
    er_t[h * BN_ + n0 + n] = (sEr[0][n] + sEr[1][n] + sEr[2][n] + sEr[3][n]) * LOG2E;
  }
  const int b8h = (nt >> 4) * 8 + h;
  const int jb  = (nt & 15) * 2;
#pragma unroll
  for (int gi = 0; gi < 2; gi++) {
    const int g   = threadIdx.x * 2 + gi;
    const int jsl = g >> 8, ff = (g >> 6) & 3, gl = g & 63;
    const int glr = gl & 15, glk = gl >> 4;
    bf16x8 v = *(const bf16x8*)(&sT[ff * 16 + glr][jsl * 32 + glk * 8]);
    *(bf16x8*)(hAg + (((size_t)b8h * 32 + jb + jsl) * 4 + ff) * 512 + gl * 8) = v;
  }
}

// K2 v13: pure-register core, depth-4 pipeline. CHANGES vs v11/v12:
//  (1) exp via __builtin_amdgcn_exp2f (schedulable) instead of inline asm
//      (asm acted as a per-step scheduling fence chain — the invariant stall).
//  (2) 8-wave blocks = all 8 heads; grid 256 = 1/CU; cmat tile read once.
#define PREFX(sn, Hd, E0d, E1d, Cd)                                   \
  {                                                                   \
    const short* hs_ = hW + (size_t)(sn) * 2048;                      \
    Hd[0] = *(const bf16x8*)(hs_);                                    \
    Hd[1] = *(const bf16x8*)(hs_ + 512);                              \
    Hd[2] = *(const bf16x8*)(hs_ + 1024);                             \
    Hd[3] = *(const bf16x8*)(hs_ + 1536);                             \
    E0d   = *(const f32x4*)(erp + (sn) * 32);                         \
    E1d   = *(const f32x4*)(erp + (sn) * 32 + 4);                     \
    Cd[0] = *(const bf16x8*)(cmW + (size_t)(sn) * 1024);              \
    Cd[1] = *(const bf16x8*)(cmW + (size_t)(sn) * 1024 + 512);        \
  }

#define COMP2(Hu, Cu, E0u, E1u)                                                \
  {                                                                            \
    bf16x8 pfA, pfB;                                                           \
    _Pragma("unroll")                                                          \
    for (int q = 0; q < 4; q++) {                                              \
      const float e0 = E0u[q], e1 = E1u[q];                                    \
      float sA  = el0 + e0, sA2 = el0 + e1;                                    \
      float sB  = el1 + e0, sB2 = el1 + e1;                                    \
      float vA  = fmaf(0.6f, sA,  bf2f(Cu[0][q]));                             \
      vA  = fmaf(0.4f, fabsf(sA),  vA);                                        \
      float vA2 = fmaf(0.6f, sA2, bf2f(Cu[0][q + 4]));                         \
      vA2 = fmaf(0.4f, fabsf(sA2), vA2);                                       \
      float vB  = fmaf(0.6f, sB,  bf2f(Cu[1][q]));                             \
      vB  = fmaf(0.4f, fabsf(sB),  vB);                                        \
      float vB2 = fmaf(0.6f, sB2, bf2f(Cu[1][q + 4]));                         \
      vB2 = fmaf(0.4f, fabsf(sB2), vB2);                                       \
      pfA[q]     = f2bf(__builtin_amdgcn_exp2f(vA));                           \
      pfA[q + 4] = f2bf(__builtin_amdgcn_exp2f(vA2));                          \
      pfB[q]     = f2bf(__builtin_amdgcn_exp2f(vB));                           \
      pfB[q + 4] = f2bf(__builtin_amdgcn_exp2f(vB2));                          \
    }                                                                          \
    __builtin_amdgcn_s_setprio(1);                                             \
    accSA   = __builtin_amdgcn_mfma_f32_16x16x32_bf16(ones, pfA, accSA, 0,0,0);\
    accSB   = __builtin_amdgcn_mfma_f32_16x16x32_bf16(ones, pfB, accSB, 0,0,0);\
    accA[0] = __builtin_amdgcn_mfma_f32_16x16x32_bf16(Hu[0], pfA, accA[0],0,0,0);\
    accB[0] = __builtin_amdgcn_mfma_f32_16x16x32_bf16(Hu[0], pfB, accB[0],0,0,0);\
    accA[1] = __builtin_amdgcn_mfma_f32_16x16x32_bf16(Hu[1], pfA, accA[1],0,0,0);\
    accB[1] = __builtin_amdgcn_mfma_f32_16x16x32_bf16(Hu[1], pfB, accB[1],0,0,0);\
    accA[2] = __builtin_amdgcn_mfma_f32_16x16x32_bf16(Hu[2], pfA, accA[2],0,0,0);\
    accB[2] = __builtin_amdgcn_mfma_f32_16x16x32_bf16(Hu[2], pfB, accB[2],0,0,0);\
    accA[3] = __builtin_amdgcn_mfma_f32_16x16x32_bf16(Hu[3], pfA, accA[3],0,0,0);\
    accB[3] = __builtin_amdgcn_mfma_f32_16x16x32_bf16(Hu[3], pfB, accB[3],0,0,0);\
    __builtin_amdgcn_s_setprio(0);                                             \
  }

__global__ __launch_bounds__(512, 2) void k_attn(
    const short* __restrict__ hAg, const float* __restrict__ el_t,
    const float* __restrict__ er_t, const short* __restrict__ cmat,
    float* __restrict__ out) {
  const int bid = blockIdx.x;
  const int b  = bid & 7;           // XCD = bid % 8
  const int it = bid >> 3;          // 0..31
  const int t  = threadIdx.x;       // 512 threads = 8 waves
  const int h  = t >> 6;            // wave = head
  const int l  = t & 63;
  const int lr = l & 15, lk = l >> 4;
  const int i0 = it * 32;
  const size_t bn = (size_t)b * N_;

  const float el0 = el_t[h * BN_ + bn + i0 + lr];
  const float el1 = el_t[h * BN_ + bn + i0 + 16 + lr];
  const float* erp = er_t + h * BN_ + bn + lk * 8;
  const short* hW  = hAg + (size_t)(b * 8 + h) * 65536 + l * 8;
  const short* cmW = cmat + (size_t)(b * 32 + it) * 32768 + l * 8;

  bf16x8 HA[4], HB[4], HC[4], HD[4];
  bf16x8 cA[2], cB[2], cC[2], cD[2];
  f32x4 eA0, eA1, eB0, eB1, eC0, eC1, eD0, eD1;
  f32x4 accA[4] = {}, accB[4] = {};
  f32x4 accSA = {}, accSB = {};
  bf16x8 ones;
#pragma unroll
  for (int e = 0; e < 8; e++) ones[e] = (short)0x3F80;

  PREFX(0, HA, eA0, eA1, cA);
  PREFX(1, HB, eB0, eB1, cB);
  PREFX(2, HC, eC0, eC1, cC);
  PREFX(3, HD, eD0, eD1, cD);

  for (int s = 0; s < 32; s += 4) {  // branchless: tail prefetches read pads
    COMP2(HA, cA, eA0, eA1);  PREFX(s + 4, HA, eA0, eA1, cA);
    COMP2(HB, cB, eB0, eB1);  PREFX(s + 5, HB, eB0, eB1, cB);
    COMP2(HC, cC, eC0, eC1);  PREFX(s + 6, HC, eC0, eC1, cC);
    COMP2(HD, cD, eD0, eD1);  PREFX(s + 7, HD, eD0, eD1, cD);
  }

  const float invA = 1.0f / accSA[0];
  const float invB = 1.0f / accSB[0];
  const size_t rowA = bn + i0 + lr;
  const size_t rowB = rowA + 16;
#pragma unroll
  for (int ff = 0; ff < 4; ff++) {
    f32x4 va = accA[ff], vb = accB[ff];
    va[0]*=invA; va[1]*=invA; va[2]*=invA; va[3]*=invA;
    vb[0]*=invB; vb[1]*=invB; vb[2]*=invB; vb[3]*=invB;
    *(f32x4*)(out + rowA * HF_ + h * 64 + ff * 16 + lk * 4) = va;
    *(f32x4*)(out + rowB * HF_ + h * 64 + ff * 16 + lk * 4) = vb;
  }
}

extern "C" void kernel_launch(void* const* d_in, const int* in_sizes, int n_in,
                              void* d_out, int out_size, void* d_ws, size_t ws_size,
                              hipStream_t stream) {
  const float* x     = (const float*)d_in[0];
  const int*   adj   = (const int*)  d_in[1];
  const float* prior = (const float*)d_in[2];
  const float* W     = (const float*)d_in[3];
  const float* aL    = (const float*)d_in[4];
  const float* aR    = (const float*)d_in[5];
  const float* es    = (const float*)d_in[6];
  float* out = (float*)d_out;

  char* ws = (char*)d_ws;
  short* hAg  = (short*)ws;                                 //  0 MB,  8 MB
  short* xb   = (short*)(ws + 8u  * 1024 * 1024);           //  8 MB,  4 MB
  short* Wt   = (short*)(ws + 12u * 1024 * 1024);           // 12 MB, 256 KB
  float* el_t = (float*)(ws + 12u * 1024 * 1024 + 262144);  // 256 KB
  float* er_t = (float*)(ws + 12u * 1024 * 1024 + 524288);  // 256 KB
  short* cmat = (short*)(ws + 13u * 1024 * 1024);           // 13 MB, 16 MB (+pad)

  hipLaunchKernelGGL(k_prep, dim3(1792), dim3(256), 0, stream,
                     x, W, prior, adj, es, xb, Wt, cmat);
  hipLaunchKernelGGL(k_h,   dim3(128, 8), dim3(256), 0, stream,
                     Wt, xb, aL, aR, hAg, el_t, er_t);
  hipLaunchKernelGGL(k_attn, dim3(256), dim3(512), 0, stream,
                     hAg, el_t, er_t, cmat, out);
}